// Round 3
// baseline (44342.770 us; speedup 1.0000x reference)
//
#include <hip/hip_runtime.h>
#include <hip/hip_fp16.h>

// LayerNormLSTMCell: B=128, T=512, D=512, U=512, 4 gates (f,g,i,o), shared LN.
// Numerics: split-bf16 (hi+lo) on both operands of every GEMM, 3-product MFMA
// (hi*hi + lo*hi + hi*lo) ~= fp32; xz stored fp16 (eps 2^-11, keeps ws <= 262 MiB
// -- round 2's fp32 xz at 517 MiB overflowed ws and page-faulted).
//   k_prep_w  : Wh -> VGPR-fragment-ordered bf16 hi/lo pair buffers
//   k_gemm_xz : xz[b*T+t][2048] = x @ Wx^T  fp32-in (split in LDS), fp16-out
//   k_lstm    : persistent, 16 clusters x 16 WGs x 256 thr; Wh hi+lo resident
//               in VGPRs (256 regs; 1 wave/SIMD design so free);
//               2 cluster spin-barriers/step; c/h update replicated per WG.

typedef unsigned short ushort_t;
typedef __attribute__((ext_vector_type(8))) short short8;
typedef __attribute__((ext_vector_type(4))) float f32x4;

#define Bsz 128
#define Tn  512
#define Un  512
#define NU  2048
#define NC  16     // clusters
#define WPC 16     // WGs per cluster
#define BPC 8      // batches per cluster

__device__ __forceinline__ ushort_t f2bf(float f){
  unsigned u = __float_as_uint(f);
  u = u + 0x7fffu + ((u >> 16) & 1u);   // RNE
  return (ushort_t)(u >> 16);
}
__device__ __forceinline__ float bf2f(ushort_t h){
  return __uint_as_float(((unsigned)h) << 16);
}
__device__ __forceinline__ float sigf(float x){ return 1.0f/(1.0f + __expf(-x)); }
__device__ __forceinline__ float tanh_fast(float x){
  float ax = fabsf(x);
  float e  = __expf(-2.0f*ax);          // in (0,1], no overflow
  float r  = (1.0f - e)/(1.0f + e);
  return x >= 0.0f ? r : -r;
}

// ---------------- weight prep: Wh -> fragment-ordered hi/lo ----------------
// layout: idx = ((wslot*32 + i)*64 + lane)*8 + j, wslot=wid*4+wave, i=kiter*2+nt
//   lane holds B-frag: n = wid*128+wave*32+nt*16+(lane&15), k = kiter*32+(lane>>4)*8+j
__global__ void k_prep_w(const float* __restrict__ Wf, const float* __restrict__ Wg,
                         const float* __restrict__ Wi, const float* __restrict__ Wo,
                         ushort_t* __restrict__ wh_hi, ushort_t* __restrict__ wh_lo){
  int idx = blockIdx.x*blockDim.x + threadIdx.x;
  if (idx >= 1048576) return;
  const float* Wp[4] = {Wf, Wg, Wi, Wo};
  int j = idx & 7;
  int lane = (idx >> 3) & 63;
  int i = (idx >> 9) & 31;
  int wslot = idx >> 14;
  int kiter = i >> 1, nt = i & 1;
  int wid = wslot >> 2, wave = wslot & 3;
  int n = wid*128 + wave*32 + nt*16 + (lane & 15);
  int k = kiter*32 + (lane >> 4)*8 + j;
  int gate = n >> 9, u = n & 511;
  float w = Wp[gate][u*1024 + k];
  ushort_t hi = f2bf(w);
  wh_hi[idx] = hi;
  wh_lo[idx] = f2bf(w - bf2f(hi));
}

// ---------------- xz = x @ Wx^T  (split-bf16 MFMA, 128x128 tile, BK=32) ----------------
__global__ __launch_bounds__(256,2) void k_gemm_xz(const float* __restrict__ A,
    const float* __restrict__ Wf, const float* __restrict__ Wg,
    const float* __restrict__ Wi, const float* __restrict__ Wo,
    __half* __restrict__ C){
  __shared__ __align__(16) ushort_t Ah[128*32];
  __shared__ __align__(16) ushort_t Al[128*32];
  __shared__ __align__(16) ushort_t Bh[128*32];
  __shared__ __align__(16) ushort_t Bl[128*32];
  const int tid  = threadIdx.x;
  const int lane = tid & 63, wave = tid >> 6;
  const int quad = lane >> 4, l15 = lane & 15;
  const int wm = wave >> 1, wn = wave & 1;
  const int m0 = blockIdx.x * 128, n0 = blockIdx.y * 128;
  const float* Wp = (n0 < 512) ? Wf : (n0 < 1024) ? Wg : (n0 < 1536) ? Wi : Wo;
  const int u0 = n0 & 511;
  f32x4 acc[4][4];
  #pragma unroll
  for (int a=0;a<4;a++)
    #pragma unroll
    for (int b=0;b<4;b++) acc[a][b] = (f32x4){0.f,0.f,0.f,0.f};

  for (int kc = 0; kc < 512; kc += 32){
    __syncthreads();
    #pragma unroll
    for (int p=0; p<4; p++){
      int slot = p*256 + tid;
      int row = slot >> 3, seg = slot & 7;
      float4 va = *(const float4*)(A  + (size_t)(m0+row)*512  + kc + seg*4);
      float4 vb = *(const float4*)(Wp + (size_t)(u0+row)*1024 + 512 + kc + seg*4);
      ushort4 ah, al, bh, bl;
      ah.x=f2bf(va.x); al.x=f2bf(va.x-bf2f(ah.x));
      ah.y=f2bf(va.y); al.y=f2bf(va.y-bf2f(ah.y));
      ah.z=f2bf(va.z); al.z=f2bf(va.z-bf2f(ah.z));
      ah.w=f2bf(va.w); al.w=f2bf(va.w-bf2f(ah.w));
      bh.x=f2bf(vb.x); bl.x=f2bf(vb.x-bf2f(bh.x));
      bh.y=f2bf(vb.y); bl.y=f2bf(vb.y-bf2f(bh.y));
      bh.z=f2bf(vb.z); bl.z=f2bf(vb.z-bf2f(bh.z));
      bh.w=f2bf(vb.w); bl.w=f2bf(vb.w-bf2f(bh.w));
      *(ushort4*)(Ah + slot*4) = ah;
      *(ushort4*)(Al + slot*4) = al;
      *(ushort4*)(Bh + slot*4) = bh;
      *(ushort4*)(Bl + slot*4) = bl;
    }
    __syncthreads();
    short8 afh[4], afl[4], bfh[4], bfl[4];
    #pragma unroll
    for (int ti=0; ti<4; ti++){
      afh[ti] = *(const short8*)(Ah + (wm*64 + ti*16 + l15)*32 + quad*8);
      afl[ti] = *(const short8*)(Al + (wm*64 + ti*16 + l15)*32 + quad*8);
    }
    #pragma unroll
    for (int tj=0; tj<4; tj++){
      bfh[tj] = *(const short8*)(Bh + (wn*64 + tj*16 + l15)*32 + quad*8);
      bfl[tj] = *(const short8*)(Bl + (wn*64 + tj*16 + l15)*32 + quad*8);
    }
    #pragma unroll
    for (int ti=0; ti<4; ti++)
      #pragma unroll
      for (int tj=0; tj<4; tj++){
        acc[ti][tj] = __builtin_amdgcn_mfma_f32_16x16x32_bf16(afh[ti], bfh[tj], acc[ti][tj], 0,0,0);
        acc[ti][tj] = __builtin_amdgcn_mfma_f32_16x16x32_bf16(afl[ti], bfh[tj], acc[ti][tj], 0,0,0);
        acc[ti][tj] = __builtin_amdgcn_mfma_f32_16x16x32_bf16(afh[ti], bfl[tj], acc[ti][tj], 0,0,0);
      }
  }
  #pragma unroll
  for (int ti=0; ti<4; ti++)
    #pragma unroll
    for (int tj=0; tj<4; tj++)
      #pragma unroll
      for (int r=0; r<4; r++){
        int m = m0 + wm*64 + ti*16 + quad*4 + r;
        int n = n0 + wn*64 + tj*16 + l15;
        C[(size_t)m*NU + n] = __float2half(acc[ti][tj][r]);
      }
}

// ---------------- persistent LSTM ----------------
__global__ __launch_bounds__(256,1) void k_lstm(
    const ushort_t* __restrict__ wh_hi_g, const ushort_t* __restrict__ wh_lo_g,
    const __half* __restrict__ xz,
    const float* __restrict__ bfp, const float* __restrict__ bgp,
    const float* __restrict__ bip, const float* __restrict__ bop,
    const float* __restrict__ gamma, const float* __restrict__ beta,
    const float* __restrict__ h0, const float* __restrict__ c0,
    float* __restrict__ actbuf, float* __restrict__ zpart,
    unsigned* __restrict__ bars, float* __restrict__ out)
{
  const int bid = blockIdx.x;
  const int cid = bid & 15;          // cluster: members share bid%16 -> same XCD (bid%8)
  const int wid = bid >> 4;          // 0..15 within cluster; owns units [wid*128, wid*128+128)
  const int tid = threadIdx.x;
  const int wave = tid >> 6, lane = tid & 63;
  const int quad = lane >> 4, l15 = lane & 15;
  const int gate = wid >> 2;

  __shared__ __align__(16) ushort_t h_hi[16][520];   // rows 8..15 stay zero (M=8 pad to 16)
  __shared__ __align__(16) ushort_t h_lo[16][520];
  __shared__ float gamma_lds[512], beta_lds[512];
  __shared__ float wavepart[4][8][2];

  for (int i = tid; i < 16*520; i += 256){
    int r = i / 520, u = i - r*520;
    float v = (r < BPC && u < 512) ? h0[(cid*BPC + r)*512 + u] : 0.0f;
    ushort_t hh = f2bf(v);
    h_hi[r][u] = hh;
    h_lo[r][u] = f2bf(v - bf2f(hh));
  }
  for (int i = tid; i < 512; i += 256){ gamma_lds[i] = gamma[i]; beta_lds[i] = beta[i]; }

  // replicated c-state: thread owns (b_loc, 16 units)
  const int b_loc = tid >> 5;
  const int uc = (tid & 31) << 4;
  float c[16];
  #pragma unroll
  for (int i=0;i<16;i++) c[i] = c0[(cid*BPC + b_loc)*512 + uc + i];

  // VGPR-resident Wh B-fragments, hi+lo: 256 VGPRs/lane (free: 1 wave/SIMD design)
  short8 wrh[32], wrl[32];
  {
    const ushort_t* wph = wh_hi_g + (size_t)(wid*4 + wave)*16384 + lane*8;
    const ushort_t* wpl = wh_lo_g + (size_t)(wid*4 + wave)*16384 + lane*8;
    #pragma unroll
    for (int i=0;i<32;i++){
      wrh[i] = *(const short8*)(wph + (size_t)i*512);
      wrl[i] = *(const short8*)(wpl + (size_t)i*512);
    }
  }

  float bias_r[2], gam_r[2], bet_r[2];
  int ng_[2];
  #pragma unroll
  for (int nt=0; nt<2; nt++){
    int ng = wid*128 + wave*32 + nt*16 + l15;
    ng_[nt] = ng;
    int u = ng & 511;
    const float* bp = (gate==0)? bfp : (gate==1)? bgp : (gate==2)? bip : bop;
    bias_r[nt] = bp[u];
    gam_r[nt] = gamma[u]; bet_r[nt] = beta[u];
  }
  const bool bvalid = (quad < 2);
  const int b_base = quad*4;
  unsigned* bar0 = bars + cid*32;
  unsigned* bar1 = bars + cid*32 + 16;

  __syncthreads();

  for (int t = 0; t < Tn; ++t){
    // ---- phase 1: z = h @ Wh^T + xz + bias  (split-bf16, 3 products) ----
    float xzv[2][4];
    #pragma unroll
    for (int nt=0; nt<2; nt++)
      #pragma unroll
      for (int r=0; r<4; r++){
        if (bvalid){
          int b = cid*BPC + b_base + r;
          xzv[nt][r] = __half2float(xz[((size_t)b*Tn + t)*NU + ng_[nt]]);
        } else xzv[nt][r] = 0.0f;
      }
    f32x4 acc0 = (f32x4){0.f,0.f,0.f,0.f}, acc1 = (f32x4){0.f,0.f,0.f,0.f};
    #pragma unroll
    for (int ki=0; ki<16; ki++){
      short8 afh = *(const short8*)(&h_hi[l15][ki*32 + quad*8]);
      short8 afl = *(const short8*)(&h_lo[l15][ki*32 + quad*8]);
      acc0 = __builtin_amdgcn_mfma_f32_16x16x32_bf16(afh, wrh[2*ki+0], acc0, 0,0,0);
      acc0 = __builtin_amdgcn_mfma_f32_16x16x32_bf16(afl, wrh[2*ki+0], acc0, 0,0,0);
      acc0 = __builtin_amdgcn_mfma_f32_16x16x32_bf16(afh, wrl[2*ki+0], acc0, 0,0,0);
      acc1 = __builtin_amdgcn_mfma_f32_16x16x32_bf16(afh, wrh[2*ki+1], acc1, 0,0,0);
      acc1 = __builtin_amdgcn_mfma_f32_16x16x32_bf16(afl, wrh[2*ki+1], acc1, 0,0,0);
      acc1 = __builtin_amdgcn_mfma_f32_16x16x32_bf16(afh, wrl[2*ki+1], acc1, 0,0,0);
    }
    float z[2][4];
    #pragma unroll
    for (int r=0;r<4;r++){
      z[0][r] = bvalid ? (acc0[r] + xzv[0][r] + bias_r[0]) : 0.0f;
      z[1][r] = bvalid ? (acc1[r] + xzv[1][r] + bias_r[1]) : 0.0f;
    }
    // wave-local stats over its 32 units (per batch r)
    float sum[4], ssq[4];
    #pragma unroll
    for (int r=0;r<4;r++){
      float s = z[0][r] + z[1][r];
      float q = z[0][r]*z[0][r] + z[1][r]*z[1][r];
      #pragma unroll
      for (int off=1; off<16; off<<=1){ s += __shfl_xor(s, off); q += __shfl_xor(q, off); }
      sum[r]=s; ssq[r]=q;
    }
    if (l15 == 0 && bvalid){
      #pragma unroll
      for (int r=0;r<4;r++){
        wavepart[wave][b_base + r][0] = sum[r];
        wavepart[wave][b_base + r][1] = ssq[r];
      }
    }
    __syncthreads();
    if (tid < 16){
      int b = tid >> 1, w = tid & 1;
      float v = wavepart[0][b][w] + wavepart[1][b][w] + wavepart[2][b][w] + wavepart[3][b][w];
      zpart[((cid*WPC + wid)*BPC + b)*2 + w] = v;
    }
    __threadfence();
    __syncthreads();
    if (tid == 0){
      unsigned target = (unsigned)(t+1)*WPC;
      __hip_atomic_fetch_add(bar0, 1u, __ATOMIC_ACQ_REL, __HIP_MEMORY_SCOPE_AGENT);
      while (__hip_atomic_load(bar0, __ATOMIC_ACQUIRE, __HIP_MEMORY_SCOPE_AGENT) < target)
        __builtin_amdgcn_s_sleep(2);
    }
    __syncthreads();
    __threadfence();

    // ---- phase 2: LN(z) + activation, publish acts ----
    if (bvalid){
      const float2* zp = (const float2*)zpart;
      float mean[4], rstd[4];
      #pragma unroll
      for (int r=0;r<4;r++){
        float S=0.f, Q=0.f;
        #pragma unroll
        for (int j=0;j<4;j++){
          float2 v = zp[(cid*WPC + gate*4 + j)*BPC + b_base + r];
          S += v.x; Q += v.y;
        }
        float m_ = S * (1.0f/512.0f);
        float var = Q * (1.0f/512.0f) - m_*m_;
        mean[r] = m_; rstd[r] = rsqrtf(var + 1e-3f);
      }
      #pragma unroll
      for (int nt=0;nt<2;nt++)
        #pragma unroll
        for (int r=0;r<4;r++){
          float zn = (z[nt][r] - mean[r]) * rstd[r] * gam_r[nt] + bet_r[nt];
          float a = (gate==1) ? tanh_fast(zn) : sigf(zn);
          actbuf[(size_t)(cid*BPC + b_base + r)*NU + ng_[nt]] = a;
        }
    }
    __threadfence();
    __syncthreads();
    if (tid == 0){
      unsigned target = (unsigned)(t+1)*WPC;
      __hip_atomic_fetch_add(bar1, 1u, __ATOMIC_ACQ_REL, __HIP_MEMORY_SCOPE_AGENT);
      while (__hip_atomic_load(bar1, __ATOMIC_ACQUIRE, __HIP_MEMORY_SCOPE_AGENT) < target)
        __builtin_amdgcn_s_sleep(2);
    }
    __syncthreads();
    __threadfence();

    // ---- phase 3: replicated c/h update (all 512 units x 8 batches per WG) ----
    {
      const float* ab = actbuf + (size_t)(cid*BPC + b_loc)*NU;
      float fg[16], gg[16], ig[16], og[16], cn[16];
      #pragma unroll
      for (int ch=0; ch<4; ch++){
        float4 vf = *(const float4*)(ab +    0 + uc + ch*4);
        float4 vg = *(const float4*)(ab +  512 + uc + ch*4);
        float4 vi = *(const float4*)(ab + 1024 + uc + ch*4);
        float4 vo = *(const float4*)(ab + 1536 + uc + ch*4);
        fg[ch*4+0]=vf.x; fg[ch*4+1]=vf.y; fg[ch*4+2]=vf.z; fg[ch*4+3]=vf.w;
        gg[ch*4+0]=vg.x; gg[ch*4+1]=vg.y; gg[ch*4+2]=vg.z; gg[ch*4+3]=vg.w;
        ig[ch*4+0]=vi.x; ig[ch*4+1]=vi.y; ig[ch*4+2]=vi.z; ig[ch*4+3]=vi.w;
        og[ch*4+0]=vo.x; og[ch*4+1]=vo.y; og[ch*4+2]=vo.z; og[ch*4+3]=vo.w;
      }
      float ls=0.f, lq=0.f;
      #pragma unroll
      for (int i=0;i<16;i++){
        cn[i] = c[i]*fg[i] + gg[i]*ig[i];
        ls += cn[i]; lq += cn[i]*cn[i];
      }
      #pragma unroll
      for (int off=1; off<32; off<<=1){ ls += __shfl_xor(ls, off); lq += __shfl_xor(lq, off); }
      float m_ = ls*(1.0f/512.0f);
      float var = lq*(1.0f/512.0f) - m_*m_;
      float rs = rsqrtf(var + 1e-3f);
      #pragma unroll
      for (int i=0;i<16;i++){
        float cl = (cn[i]-m_)*rs*gamma_lds[uc+i] + beta_lds[uc+i];
        c[i] = cl;
        float h = og[i]*tanh_fast(cl);
        ushort_t hh = f2bf(h);
        h_hi[b_loc][uc+i] = hh;
        h_lo[b_loc][uc+i] = f2bf(h - bf2f(hh));
        if (wid == 0) out[((size_t)(cid*BPC + b_loc)*Tn + t)*Un + uc + i] = h;
      }
    }
    __syncthreads();   // h_lds ready for next step's MFMA
  }
}

extern "C" void kernel_launch(void* const* d_in, const int* in_sizes, int n_in,
                              void* d_out, int out_size, void* d_ws, size_t ws_size,
                              hipStream_t stream){
  const float* x     = (const float*)d_in[0];
  const float* h0    = (const float*)d_in[1];
  const float* c0    = (const float*)d_in[2];
  const float* Wf    = (const float*)d_in[3];
  const float* bf_   = (const float*)d_in[4];
  const float* Wg    = (const float*)d_in[5];
  const float* bg_   = (const float*)d_in[6];
  const float* Wi    = (const float*)d_in[7];
  const float* bi_   = (const float*)d_in[8];
  const float* Wo    = (const float*)d_in[9];
  const float* bo_   = (const float*)d_in[10];
  const float* gamma = (const float*)d_in[11];
  const float* beta  = (const float*)d_in[12];

  char* ws = (char*)d_ws;
  __half*   xz    = (__half*)(ws);                             // 256 MiB
  ushort_t* wh_hi = (ushort_t*)(ws + (256ull<<20));            // 2 MiB
  ushort_t* wh_lo = (ushort_t*)(ws + (258ull<<20));            // 2 MiB
  float*    actbuf= (float*)(ws + (260ull<<20));               // 1 MiB
  float*    zpart = (float*)(ws + (261ull<<20));               // 16 KiB
  unsigned* bars  = (unsigned*)(ws + (261ull<<20) + (64ull<<10)); // 4 KiB
  float* out = (float*)d_out;

  hipMemsetAsync(bars, 0, 4096, stream);
  k_prep_w<<<4096, 256, 0, stream>>>(Wf, Wg, Wi, Wo, wh_hi, wh_lo);
  dim3 g(Bsz*Tn/128, NU/128);
  k_gemm_xz<<<g, 256, 0, stream>>>(x, Wf, Wg, Wi, Wo, xz);
  k_lstm<<<256, 256, 0, stream>>>(wh_hi, wh_lo, xz, bf_, bg_, bi_, bo_, gamma, beta, h0, c0,
                                  actbuf, zpart, bars, out);
}

// Round 5
// 14755.634 us; speedup vs baseline: 3.0051x; 3.0051x over previous
//
#include <hip/hip_runtime.h>
#include <hip/hip_fp16.h>

// LayerNormLSTMCell: B=128, T=512, D=512, U=512, 4 gates (f,g,i,o), shared LN.
// Numerics: split-bf16 (hi+lo) on both operands of every GEMM, 3-product MFMA
// (hi*hi + lo*hi + hi*lo) ~= fp32; xz stored fp16. PASSED r3 at absmax 0.0039.
// R5 sync redesign: r4's relaxed flag-barrier raced (data stores vs flag have
// no ordering at LLC under RELAXED; replay re-validation failed). Now ALL
// cross-WG exchange is seqlock-tagged: each exchanged float is one 8-byte
// atomic word (tag=t+1 in high 32b | value bits in low 32b), double-buffered
// by step parity. Correct under ANY ordering: per-word atomicity + parity
// buffers + dependency-bounded skew (<2 steps). No fences, no flags, no L2
// maintenance. Tag buffers memset at launch start (tag 0 never matches t+1).

typedef unsigned short ushort_t;
typedef unsigned long long u64;
typedef __attribute__((ext_vector_type(8))) short short8;
typedef __attribute__((ext_vector_type(4))) float f32x4;

#define Bsz 128
#define Tn  512
#define Un  512
#define NU  2048
#define NC  16     // clusters
#define WPC 16     // WGs per cluster
#define BPC 8      // batches per cluster

__device__ __forceinline__ ushort_t f2bf(float f){
  unsigned u = __float_as_uint(f);
  u = u + 0x7fffu + ((u >> 16) & 1u);   // RNE
  return (ushort_t)(u >> 16);
}
__device__ __forceinline__ float bf2f(ushort_t h){
  return __uint_as_float(((unsigned)h) << 16);
}
__device__ __forceinline__ float sigf(float x){ return 1.0f/(1.0f + __expf(-x)); }
__device__ __forceinline__ float tanh_fast(float x){
  float ax = fabsf(x);
  float e  = __expf(-2.0f*ax);          // in (0,1], no overflow
  float r  = (1.0f - e)/(1.0f + e);
  return x >= 0.0f ? r : -r;
}

// ---- seqlock-tagged 8B exchange (relaxed agent-scope; atomicity is the only
//      property used -- value and tag always travel together) ----
__device__ __forceinline__ void st_tag(u64* p, float v, unsigned tag){
  u64 w = ((u64)tag << 32) | (u64)__float_as_uint(v);
  __hip_atomic_store(p, w, __ATOMIC_RELAXED, __HIP_MEMORY_SCOPE_AGENT);
}
__device__ __forceinline__ u64 ld_u64(const u64* p){
  return __hip_atomic_load(p, __ATOMIC_RELAXED, __HIP_MEMORY_SCOPE_AGENT);
}
__device__ __forceinline__ float val_of(u64 w){ return __uint_as_float((unsigned)w); }

// ---------------- weight prep: Wh -> fragment-ordered hi/lo ----------------
__global__ void k_prep_w(const float* __restrict__ Wf, const float* __restrict__ Wg,
                         const float* __restrict__ Wi, const float* __restrict__ Wo,
                         ushort_t* __restrict__ wh_hi, ushort_t* __restrict__ wh_lo){
  int idx = blockIdx.x*blockDim.x + threadIdx.x;
  if (idx >= 1048576) return;
  const float* Wp[4] = {Wf, Wg, Wi, Wo};
  int j = idx & 7;
  int lane = (idx >> 3) & 63;
  int i = (idx >> 9) & 31;
  int wslot = idx >> 14;
  int kiter = i >> 1, nt = i & 1;
  int wid = wslot >> 2, wave = wslot & 3;
  int n = wid*128 + wave*32 + nt*16 + (lane & 15);
  int k = kiter*32 + (lane >> 4)*8 + j;
  int gate = n >> 9, u = n & 511;
  float w = Wp[gate][u*1024 + k];
  ushort_t hi = f2bf(w);
  wh_hi[idx] = hi;
  wh_lo[idx] = f2bf(w - bf2f(hi));
}

// ---------------- xz = x @ Wx^T  (split-bf16 MFMA, 128x128 tile, BK=32) ----------------
__global__ __launch_bounds__(256,2) void k_gemm_xz(const float* __restrict__ A,
    const float* __restrict__ Wf, const float* __restrict__ Wg,
    const float* __restrict__ Wi, const float* __restrict__ Wo,
    __half* __restrict__ C){
  __shared__ __align__(16) ushort_t Ah[128*32];
  __shared__ __align__(16) ushort_t Al[128*32];
  __shared__ __align__(16) ushort_t Bh[128*32];
  __shared__ __align__(16) ushort_t Bl[128*32];
  const int tid  = threadIdx.x;
  const int lane = tid & 63, wave = tid >> 6;
  const int quad = lane >> 4, l15 = lane & 15;
  const int wm = wave >> 1, wn = wave & 1;
  const int m0 = blockIdx.x * 128, n0 = blockIdx.y * 128;
  const float* Wp = (n0 < 512) ? Wf : (n0 < 1024) ? Wg : (n0 < 1536) ? Wi : Wo;
  const int u0 = n0 & 511;
  f32x4 acc[4][4];
  #pragma unroll
  for (int a=0;a<4;a++)
    #pragma unroll
    for (int b=0;b<4;b++) acc[a][b] = (f32x4){0.f,0.f,0.f,0.f};

  for (int kc = 0; kc < 512; kc += 32){
    __syncthreads();
    #pragma unroll
    for (int p=0; p<4; p++){
      int slot = p*256 + tid;
      int row = slot >> 3, seg = slot & 7;
      float4 va = *(const float4*)(A  + (size_t)(m0+row)*512  + kc + seg*4);
      float4 vb = *(const float4*)(Wp + (size_t)(u0+row)*1024 + 512 + kc + seg*4);
      ushort4 ah, al, bh, bl;
      ah.x=f2bf(va.x); al.x=f2bf(va.x-bf2f(ah.x));
      ah.y=f2bf(va.y); al.y=f2bf(va.y-bf2f(ah.y));
      ah.z=f2bf(va.z); al.z=f2bf(va.z-bf2f(ah.z));
      ah.w=f2bf(va.w); al.w=f2bf(va.w-bf2f(ah.w));
      bh.x=f2bf(vb.x); bl.x=f2bf(vb.x-bf2f(bh.x));
      bh.y=f2bf(vb.y); bl.y=f2bf(vb.y-bf2f(bh.y));
      bh.z=f2bf(vb.z); bl.z=f2bf(vb.z-bf2f(bh.z));
      bh.w=f2bf(vb.w); bl.w=f2bf(vb.w-bf2f(bh.w));
      *(ushort4*)(Ah + slot*4) = ah;
      *(ushort4*)(Al + slot*4) = al;
      *(ushort4*)(Bh + slot*4) = bh;
      *(ushort4*)(Bl + slot*4) = bl;
    }
    __syncthreads();
    short8 afh[4], afl[4], bfh[4], bfl[4];
    #pragma unroll
    for (int ti=0; ti<4; ti++){
      afh[ti] = *(const short8*)(Ah + (wm*64 + ti*16 + l15)*32 + quad*8);
      afl[ti] = *(const short8*)(Al + (wm*64 + ti*16 + l15)*32 + quad*8);
    }
    #pragma unroll
    for (int tj=0; tj<4; tj++){
      bfh[tj] = *(const short8*)(Bh + (wn*64 + tj*16 + l15)*32 + quad*8);
      bfl[tj] = *(const short8*)(Bl + (wn*64 + tj*16 + l15)*32 + quad*8);
    }
    #pragma unroll
    for (int ti=0; ti<4; ti++)
      #pragma unroll
      for (int tj=0; tj<4; tj++){
        acc[ti][tj] = __builtin_amdgcn_mfma_f32_16x16x32_bf16(afh[ti], bfh[tj], acc[ti][tj], 0,0,0);
        acc[ti][tj] = __builtin_amdgcn_mfma_f32_16x16x32_bf16(afl[ti], bfh[tj], acc[ti][tj], 0,0,0);
        acc[ti][tj] = __builtin_amdgcn_mfma_f32_16x16x32_bf16(afh[ti], bfl[tj], acc[ti][tj], 0,0,0);
      }
  }
  #pragma unroll
  for (int ti=0; ti<4; ti++)
    #pragma unroll
    for (int tj=0; tj<4; tj++)
      #pragma unroll
      for (int r=0; r<4; r++){
        int m = m0 + wm*64 + ti*16 + quad*4 + r;
        int n = n0 + wn*64 + tj*16 + l15;
        C[(size_t)m*NU + n] = __float2half(acc[ti][tj][r]);
      }
}

// ---------------- persistent LSTM ----------------
__global__ __launch_bounds__(256,1) void k_lstm(
    const ushort_t* __restrict__ wh_hi_g, const ushort_t* __restrict__ wh_lo_g,
    const __half* __restrict__ xz,
    const float* __restrict__ bfp, const float* __restrict__ bgp,
    const float* __restrict__ bip, const float* __restrict__ bop,
    const float* __restrict__ gamma, const float* __restrict__ beta,
    const float* __restrict__ h0, const float* __restrict__ c0,
    u64* __restrict__ actbuf, u64* __restrict__ zpart,
    float* __restrict__ out)
{
  const int bid = blockIdx.x;
  const int cid = bid & 15;          // members share bid%16 -> same XCD (bid%8)
  const int wid = bid >> 4;          // 0..15; owns units [wid*128, wid*128+128)
  const int tid = threadIdx.x;
  const int wave = tid >> 6, lane = tid & 63;
  const int quad = lane >> 4, l15 = lane & 15;
  const int gate = wid >> 2;

  __shared__ __align__(16) ushort_t h_hi[16][520];   // rows 8..15 stay zero (M=8 pad to 16)
  __shared__ __align__(16) ushort_t h_lo[16][520];
  __shared__ float gamma_lds[512], beta_lds[512];
  __shared__ float wavepart[4][8][2];

  for (int i = tid; i < 16*520; i += 256){
    int r = i / 520, u = i - r*520;
    float v = (r < BPC && u < 512) ? h0[(cid*BPC + r)*512 + u] : 0.0f;
    ushort_t hh = f2bf(v);
    h_hi[r][u] = hh;
    h_lo[r][u] = f2bf(v - bf2f(hh));
  }
  for (int i = tid; i < 512; i += 256){ gamma_lds[i] = gamma[i]; beta_lds[i] = beta[i]; }

  // replicated c-state: thread owns (b_loc, 16 units)
  const int b_loc = tid >> 5;
  const int uc = (tid & 31) << 4;
  float c[16];
  #pragma unroll
  for (int i=0;i<16;i++) c[i] = c0[(cid*BPC + b_loc)*512 + uc + i];

  // VGPR-resident Wh B-fragments, hi+lo
  short8 wrh[32], wrl[32];
  {
    const ushort_t* wph = wh_hi_g + (size_t)(wid*4 + wave)*16384 + lane*8;
    const ushort_t* wpl = wh_lo_g + (size_t)(wid*4 + wave)*16384 + lane*8;
    #pragma unroll
    for (int i=0;i<32;i++){
      wrh[i] = *(const short8*)(wph + (size_t)i*512);
      wrl[i] = *(const short8*)(wpl + (size_t)i*512);
    }
  }

  float bias_r[2], gam_r[2], bet_r[2];
  int ng_[2];
  #pragma unroll
  for (int nt=0; nt<2; nt++){
    int ng = wid*128 + wave*32 + nt*16 + l15;
    ng_[nt] = ng;
    int u = ng & 511;
    const float* bp = (gate==0)? bfp : (gate==1)? bgp : (gate==2)? bip : bop;
    bias_r[nt] = bp[u];
    gam_r[nt] = gamma[u]; bet_r[nt] = beta[u];
  }
  const bool bvalid = (quad < 2);
  const int b_base = quad*4;

  __syncthreads();

  for (int t = 0; t < Tn; ++t){
    const unsigned tag = (unsigned)(t + 1);
    const int par = t & 1;
    // ---- phase 1: z = h @ Wh^T + xz + bias  (split-bf16, 3 products) ----
    float xzv[2][4];
    #pragma unroll
    for (int nt=0; nt<2; nt++)
      #pragma unroll
      for (int r=0; r<4; r++){
        if (bvalid){
          int b = cid*BPC + b_base + r;
          xzv[nt][r] = __half2float(xz[((size_t)b*Tn + t)*NU + ng_[nt]]);
        } else xzv[nt][r] = 0.0f;
      }
    f32x4 acc0 = (f32x4){0.f,0.f,0.f,0.f}, acc1 = (f32x4){0.f,0.f,0.f,0.f};
    #pragma unroll
    for (int ki=0; ki<16; ki++){
      short8 afh = *(const short8*)(&h_hi[l15][ki*32 + quad*8]);
      short8 afl = *(const short8*)(&h_lo[l15][ki*32 + quad*8]);
      acc0 = __builtin_amdgcn_mfma_f32_16x16x32_bf16(afh, wrh[2*ki+0], acc0, 0,0,0);
      acc0 = __builtin_amdgcn_mfma_f32_16x16x32_bf16(afl, wrh[2*ki+0], acc0, 0,0,0);
      acc0 = __builtin_amdgcn_mfma_f32_16x16x32_bf16(afh, wrl[2*ki+0], acc0, 0,0,0);
      acc1 = __builtin_amdgcn_mfma_f32_16x16x32_bf16(afh, wrh[2*ki+1], acc1, 0,0,0);
      acc1 = __builtin_amdgcn_mfma_f32_16x16x32_bf16(afl, wrh[2*ki+1], acc1, 0,0,0);
      acc1 = __builtin_amdgcn_mfma_f32_16x16x32_bf16(afh, wrl[2*ki+1], acc1, 0,0,0);
    }
    float z[2][4];
    #pragma unroll
    for (int r=0;r<4;r++){
      z[0][r] = bvalid ? (acc0[r] + xzv[0][r] + bias_r[0]) : 0.0f;
      z[1][r] = bvalid ? (acc1[r] + xzv[1][r] + bias_r[1]) : 0.0f;
    }
    // wave-local stats over its 32 units (per batch r)
    float sum[4], ssq[4];
    #pragma unroll
    for (int r=0;r<4;r++){
      float s = z[0][r] + z[1][r];
      float q = z[0][r]*z[0][r] + z[1][r]*z[1][r];
      #pragma unroll
      for (int off=1; off<16; off<<=1){ s += __shfl_xor(s, off); q += __shfl_xor(q, off); }
      sum[r]=s; ssq[r]=q;
    }
    if (l15 == 0 && bvalid){
      #pragma unroll
      for (int r=0;r<4;r++){
        wavepart[wave][b_base + r][0] = sum[r];
        wavepart[wave][b_base + r][1] = ssq[r];
      }
    }
    __syncthreads();
    if (tid < 8){
      float S = wavepart[0][tid][0] + wavepart[1][tid][0] + wavepart[2][tid][0] + wavepart[3][tid][0];
      float Q = wavepart[0][tid][1] + wavepart[1][tid][1] + wavepart[2][tid][1] + wavepart[3][tid][1];
      u64* zp = zpart + (size_t)((((par*NC + cid)*WPC + wid)*BPC + tid)*2);
      st_tag(zp+0, S, tag);
      st_tag(zp+1, Q, tag);
    }
    __syncthreads();   // also prevents compiler sinking the stores below the polls

    // ---- phase 2: poll tagged z-stats, LN(z) + activation, publish tagged acts ----
    if (bvalid){
      // issue all 32 loads, then fixup-poll stragglers
      u64 zv[4][8];
      #pragma unroll
      for (int r=0;r<4;r++)
        #pragma unroll
        for (int j=0;j<4;j++){
          const u64* zp = zpart + (size_t)((((par*NC + cid)*WPC + gate*4 + j)*BPC + b_base + r)*2);
          zv[r][j*2+0] = ld_u64(zp+0);
          zv[r][j*2+1] = ld_u64(zp+1);
        }
      #pragma unroll
      for (int r=0;r<4;r++)
        #pragma unroll
        for (int j=0;j<4;j++){
          const u64* zp = zpart + (size_t)((((par*NC + cid)*WPC + gate*4 + j)*BPC + b_base + r)*2);
          while ((unsigned)(zv[r][j*2+0] >> 32) != tag) zv[r][j*2+0] = ld_u64(zp+0);
          while ((unsigned)(zv[r][j*2+1] >> 32) != tag) zv[r][j*2+1] = ld_u64(zp+1);
        }
      #pragma unroll
      for (int r=0;r<4;r++){
        float S = val_of(zv[r][0]) + val_of(zv[r][2]) + val_of(zv[r][4]) + val_of(zv[r][6]);
        float Q = val_of(zv[r][1]) + val_of(zv[r][3]) + val_of(zv[r][5]) + val_of(zv[r][7]);
        float m_ = S * (1.0f/512.0f);
        float var = Q * (1.0f/512.0f) - m_*m_;
        float rstd = rsqrtf(var + 1e-3f);
        #pragma unroll
        for (int nt=0;nt<2;nt++){
          float zn = (z[nt][r] - m_) * rstd * gam_r[nt] + bet_r[nt];
          float a = (gate==1) ? tanh_fast(zn) : sigf(zn);
          st_tag(actbuf + (size_t)(((par*NC + cid)*BPC + b_base + r))*NU + ng_[nt], a, tag);
        }
      }
    }
    __syncthreads();   // prevents sinking act stores below phase-3 polls

    // ---- phase 3: poll tagged acts, replicated c/h update ----
    {
      const u64* ab = actbuf + (size_t)(((par*NC + cid)*BPC + b_loc))*NU;
      float cn[16], og[16];
      float ls = 0.f, lq = 0.f;
      #pragma unroll
      for (int ch=0; ch<2; ch++){
        const int i0 = uc + ch*8;
        u64 av[4][8];
        #pragma unroll
        for (int g=0; g<4; g++)
          #pragma unroll
          for (int i=0; i<8; i++)
            av[g][i] = ld_u64(ab + g*512 + i0 + i);
        #pragma unroll
        for (int g=0; g<4; g++)
          #pragma unroll
          for (int i=0; i<8; i++)
            while ((unsigned)(av[g][i] >> 32) != tag) av[g][i] = ld_u64(ab + g*512 + i0 + i);
        #pragma unroll
        for (int i=0; i<8; i++){
          float fv = val_of(av[0][i]);
          float gv = val_of(av[1][i]);
          float iv = val_of(av[2][i]);
          float ov = val_of(av[3][i]);
          float cv = c[ch*8+i]*fv + gv*iv;
          cn[ch*8+i] = cv;
          og[ch*8+i] = ov;
          ls += cv; lq += cv*cv;
        }
      }
      #pragma unroll
      for (int off=1; off<32; off<<=1){ ls += __shfl_xor(ls, off); lq += __shfl_xor(lq, off); }
      float m_ = ls*(1.0f/512.0f);
      float var = lq*(1.0f/512.0f) - m_*m_;
      float rs = rsqrtf(var + 1e-3f);
      #pragma unroll
      for (int i=0;i<16;i++){
        float cl = (cn[i]-m_)*rs*gamma_lds[uc+i] + beta_lds[uc+i];
        c[i] = cl;
        float h = og[i]*tanh_fast(cl);
        ushort_t hh = f2bf(h);
        h_hi[b_loc][uc+i] = hh;
        h_lo[b_loc][uc+i] = f2bf(h - bf2f(hh));
        if (wid == 0) out[((size_t)(cid*BPC + b_loc)*Tn + t)*Un + uc + i] = h;
      }
    }
    __syncthreads();   // h_lds ready for next step's MFMA
  }
}

extern "C" void kernel_launch(void* const* d_in, const int* in_sizes, int n_in,
                              void* d_out, int out_size, void* d_ws, size_t ws_size,
                              hipStream_t stream){
  const float* x     = (const float*)d_in[0];
  const float* h0    = (const float*)d_in[1];
  const float* c0    = (const float*)d_in[2];
  const float* Wf    = (const float*)d_in[3];
  const float* bf_   = (const float*)d_in[4];
  const float* Wg    = (const float*)d_in[5];
  const float* bg_   = (const float*)d_in[6];
  const float* Wi    = (const float*)d_in[7];
  const float* bi_   = (const float*)d_in[8];
  const float* Wo    = (const float*)d_in[9];
  const float* bo_   = (const float*)d_in[10];
  const float* gamma = (const float*)d_in[11];
  const float* beta  = (const float*)d_in[12];

  char* ws = (char*)d_ws;
  __half*   xz    = (__half*)(ws);                             // 256 MiB
  ushort_t* wh_hi = (ushort_t*)(ws + (256ull<<20));            // 2 MiB
  ushort_t* wh_lo = (ushort_t*)(ws + (258ull<<20));            // 2 MiB
  u64*      actbuf= (u64*)(ws + (260ull<<20));                 // 4 MiB (tagged, 2x parity)
  u64*      zpart = (u64*)(ws + (264ull<<20));                 // 64 KiB (tagged, 2x parity)
  float* out = (float*)d_out;

  // clear tags (tag 0 never equals t+1); covers actbuf+zpart contiguously
  hipMemsetAsync(actbuf, 0, (4ull<<20) + (64ull<<10), stream);
  k_prep_w<<<4096, 256, 0, stream>>>(Wf, Wg, Wi, Wo, wh_hi, wh_lo);
  dim3 g(Bsz*Tn/128, NU/128);
  k_gemm_xz<<<g, 256, 0, stream>>>(x, Wf, Wg, Wi, Wo, xz);
  k_lstm<<<256, 256, 0, stream>>>(wh_hi, wh_lo, xz, bf_, bg_, bi_, bo_, gamma, beta, h0, c0,
                                  actbuf, zpart, out);
}